// Round 1
// 77.492 us; speedup vs baseline: 1.0158x; 1.0158x over previous
//
#include <hip/hip_runtime.h>
#include <hip/hip_bf16.h>

// Problem constants
constexpr int BN = 16384;          // batch
constexpr int DN = 64;             // nodes / input dim
constexpr int HN = 64;             // hidden

typedef __attribute__((ext_vector_type(8))) short short8;   // 8 x bf16
typedef __attribute__((ext_vector_type(4))) float f32x4;    // MFMA accumulator
typedef __attribute__((ext_vector_type(2))) float f32x2;    // packed-math pair

__device__ __forceinline__ unsigned short f2bf(float f) {
    __hip_bfloat16 h = __float2bfloat16(f);
    return *reinterpret_cast<unsigned short*>(&h);
}

__device__ __forceinline__ short8 cvt8(float4 a, float4 b) {
    short8 r;
    r[0] = (short)f2bf(a.x); r[1] = (short)f2bf(a.y);
    r[2] = (short)f2bf(a.z); r[3] = (short)f2bf(a.w);
    r[4] = (short)f2bf(b.x); r[5] = (short)f2bf(b.y);
    r[6] = (short)f2bf(b.z); r[7] = (short)f2bf(b.w);
    return r;
}

// ---------------------------------------------------------------------------
// Single fused kernel. Block = (128-row batch tile, 4 nodes), 4 waves x 32 rows.
// TRANSPOSED MFMA orientation: C[h, b] = W1'[h,:] . X[b,:]  via
// mfma(A = W1' frag, B = X frag). C/D layout (m89): col = lane&15 = b,
// row = quad*4 + reg = h. So W2[h] pairs with the REGISTER index -> epilogue
// is packed-fma over regs + a 4-lane (quad) shfl_xor reduce, and the result
// sits pre-gathered for a direct float4 store (no lds_out, no 2nd barrier).
// W1*adj fp32->bf16 conversion fused into LDS staging (no workspace, no
// w1prep dispatch).
// ---------------------------------------------------------------------------
__global__ __launch_bounds__(256, 3) void mlp_fused_kernel(
    const float* __restrict__ X,               // [B][64] fp32
    const float* __restrict__ adj,             // [64][64] fp32
    const float* __restrict__ W1,              // [64][64][64] fp32
    const float* __restrict__ W2,              // [64][64] fp32
    float* __restrict__ out)                   // [B][64] fp32
{
    const int btile = blockIdx.x & 127;        // fastest: same XCD sees same btiles across ngs
    const int ng    = blockIdx.x >> 7;         // node group (4 nodes)
    const int tid   = threadIdx.x;
    const int wave  = tid >> 6;                // 0..3
    const int lane  = tid & 63;
    const int row16 = lane & 15;               // A row (h) / B col (b) / C col (b)
    const int quad  = lane >> 4;               // k-quad for A/B; C row-quad (h)

    __shared__ unsigned short ldsW1[4 * HN * DN];  // 32 KB, XOR-swizzled bf16
    __shared__ float ldsW2[4 * HN];                // 1 KB

    // ---- X fragments (B operand): b = b0 + nt*16 + row16, d = kk*32 + quad*8 ----
    const int b0 = btile * 128 + wave * 32;
    short8 xfrag[2][2];                        // [kk][nt]
#pragma unroll
    for (int kk = 0; kk < 2; ++kk)
#pragma unroll
        for (int nt = 0; nt < 2; ++nt) {
            const float* p = X + (size_t)(b0 + nt * 16 + row16) * DN + kk * 32 + quad * 8;
            float4 v0 = *reinterpret_cast<const float4*>(p);
            float4 v1 = *reinterpret_cast<const float4*>(p + 4);
            xfrag[kk][nt] = cvt8(v0, v1);
        }

    // ---- Stage W1 * adj -> bf16 LDS, swizzled (fused w1prep) ----
    {
        const float4* w4 = reinterpret_cast<const float4*>(W1 + (size_t)ng * 4 * HN * DN);
        const float4* a4 = reinterpret_cast<const float4*>(adj + (size_t)ng * 4 * DN);
#pragma unroll
        for (int it = 0; it < 8; ++it) {
            int chunk = it * 256 + tid;        // 0..2047, 8 floats each (coalesced)
            int nl = chunk >> 9;               // node_local 0..3
            int h  = (chunk >> 3) & 63;
            int c  = chunk & 7;                // 8-elem column slot
            float4 w0 = w4[chunk * 2];
            float4 w1v = w4[chunk * 2 + 1];
            float4 a0 = a4[nl * 16 + c * 2];
            float4 a1 = a4[nl * 16 + c * 2 + 1];
            float4 m0 = {w0.x * a0.x, w0.y * a0.y, w0.z * a0.z, w0.w * a0.w};
            float4 m1 = {w1v.x * a1.x, w1v.y * a1.y, w1v.z * a1.z, w1v.w * a1.w};
            int elem = nl * 4096 + h * 64 + ((c ^ (h & 7)) << 3);
            *reinterpret_cast<short8*>(&ldsW1[elem]) = cvt8(m0, m1);
        }
        ldsW2[tid] = W2[ng * 256 + tid];
    }
    __syncthreads();

    float res[2][4];                           // [nt][j]

#pragma unroll
    for (int j = 0; j < 4; ++j) {
        // W1' fragments (A operand): h = mt*16 + row16, d = kk*32 + quad*8
        short8 wfrag[2][4];                    // [kk][mt]
#pragma unroll
        for (int kk = 0; kk < 2; ++kk)
#pragma unroll
            for (int mt = 0; mt < 4; ++mt) {
                int h = mt * 16 + row16;
                int elem = j * 4096 + h * 64 + (((kk * 4 + quad) ^ (row16 & 7)) << 3);
                wfrag[kk][mt] = *reinterpret_cast<const short8*>(&ldsW1[elem]);
            }

        // W2[node j][h] for this lane's 4 regs per mt: h = mt*16 + quad*4 + r
        float4 w2v[4];
#pragma unroll
        for (int mt = 0; mt < 4; ++mt)
            w2v[mt] = *reinterpret_cast<const float4*>(&ldsW2[j * 64 + mt * 16 + quad * 4]);

        f32x4 acc[4][2];                       // [mt(h)][nt(b)]
#pragma unroll
        for (int mt = 0; mt < 4; ++mt)
#pragma unroll
            for (int nt = 0; nt < 2; ++nt)
                acc[mt][nt] = (f32x4){0.f, 0.f, 0.f, 0.f};

#pragma unroll
        for (int kk = 0; kk < 2; ++kk)
#pragma unroll
            for (int mt = 0; mt < 4; ++mt) {
                acc[mt][0] = __builtin_amdgcn_mfma_f32_16x16x32_bf16(wfrag[kk][mt], xfrag[kk][0], acc[mt][0], 0, 0, 0);
                acc[mt][1] = __builtin_amdgcn_mfma_f32_16x16x32_bf16(wfrag[kk][mt], xfrag[kk][1], acc[mt][1], 0, 0, 0);
            }

        // epilogue: out[b, j] = sum_h relu(C[h,b]) * W2[j,h]
        // per-lane: 16 h values (4 mt x 4 regs); cross-lane only over quad (x4)
#pragma unroll
        for (int nt = 0; nt < 2; ++nt) {
            f32x2 s = (f32x2){0.f, 0.f};
#pragma unroll
            for (int mt = 0; mt < 4; ++mt) {
                f32x2 m01 = (f32x2){fmaxf(acc[mt][nt][0], 0.f), fmaxf(acc[mt][nt][1], 0.f)};
                f32x2 m23 = (f32x2){fmaxf(acc[mt][nt][2], 0.f), fmaxf(acc[mt][nt][3], 0.f)};
                s += m01 * (f32x2){w2v[mt].x, w2v[mt].y};   // v_pk_fma_f32
                s += m23 * (f32x2){w2v[mt].z, w2v[mt].w};
            }
            float r = s[0] + s[1];
            r += __shfl_xor(r, 16);            // reduce over quad (lanes +-16, +-32)
            r += __shfl_xor(r, 32);
            res[nt][j] = r;
        }
    }

    // direct store: quad 0 stores nt=0 rows, quad 1 stores nt=1 rows
    if (quad < 2) {
        float4 v = (quad == 0)
            ? make_float4(res[0][0], res[0][1], res[0][2], res[0][3])
            : make_float4(res[1][0], res[1][1], res[1][2], res[1][3]);
        *reinterpret_cast<float4*>(out + (size_t)(b0 + quad * 16 + row16) * DN + ng * 4) = v;
    }
}

extern "C" void kernel_launch(void* const* d_in, const int* in_sizes, int n_in,
                              void* d_out, int out_size, void* d_ws, size_t ws_size,
                              hipStream_t stream) {
    const float* X   = (const float*)d_in[0];   // [B, D] fp32
    const float* adj = (const float*)d_in[1];   // [D, D] fp32
    const float* W1  = (const float*)d_in[2];   // [D, H, D] fp32
    const float* W2  = (const float*)d_in[3];   // [D, H] fp32
    float* out = (float*)d_out;                 // [B, D] fp32

    (void)d_ws; (void)ws_size;                  // workspace intentionally unused

    mlp_fused_kernel<<<128 * 16, 256, 0, stream>>>(X, adj, W1, W2, out);
}

// Round 2
// 75.879 us; speedup vs baseline: 1.0374x; 1.0213x over previous
//
#include <hip/hip_runtime.h>
#include <hip/hip_bf16.h>

// Problem constants
constexpr int BN = 16384;          // batch
constexpr int DN = 64;             // nodes / input dim
constexpr int HN = 64;             // hidden

typedef __attribute__((ext_vector_type(8))) short short8;   // 8 x bf16
typedef __attribute__((ext_vector_type(4))) float f32x4;    // MFMA accumulator
typedef __attribute__((ext_vector_type(2))) float f32x2;    // packed-math pair

__device__ __forceinline__ unsigned short f2bf(float f) {
    __hip_bfloat16 h = __float2bfloat16(f);
    return *reinterpret_cast<unsigned short*>(&h);
}

__device__ __forceinline__ short8 cvt8(float4 a, float4 b) {
    short8 r;
    r[0] = (short)f2bf(a.x); r[1] = (short)f2bf(a.y);
    r[2] = (short)f2bf(a.z); r[3] = (short)f2bf(a.w);
    r[4] = (short)f2bf(b.x); r[5] = (short)f2bf(b.y);
    r[6] = (short)f2bf(b.z); r[7] = (short)f2bf(b.w);
    return r;
}

// ---------------------------------------------------------------------------
// Single fused kernel. Block = (256-row batch tile, 4 nodes), 4 waves x 64 rows.
// vs previous version: batch tile 128->256 (halves redundant W1 re-reads and
// doubles MFMA per wave), and X is staged COALESCED through LDS (contiguous
// fp32 loads -> bf16 swizzled LDS) instead of 256B-strided fragment loads --
// the strided loads cost ~4x in L1/TA transactions (16 lanes x 256B stride =
// 64 cache lines per instruction).
// TRANSPOSED MFMA orientation: C[h, b] = mfma(A = W1' frag, B = X frag);
// C/D: col = lane&15 = b, row = quad*4 + reg = h, so W2[h] pairs with the
// register index -> epilogue is packed-fma + 2 shfl_xor, direct float4 store.
// ---------------------------------------------------------------------------
__global__ __launch_bounds__(256, 2) void mlp_fused_kernel(
    const float* __restrict__ X,               // [B][64] fp32
    const float* __restrict__ adj,             // [64][64] fp32
    const float* __restrict__ W1,              // [64][64][64] fp32
    const float* __restrict__ W2,              // [64][64] fp32
    float* __restrict__ out)                   // [B][64] fp32
{
    const int btile = blockIdx.x & 63;         // fastest: same btile -> same XCD (X L2 reuse)
    const int ng    = blockIdx.x >> 6;         // node group (4 nodes), 0..15
    const int tid   = threadIdx.x;
    const int wave  = tid >> 6;                // 0..3
    const int lane  = tid & 63;
    const int row16 = lane & 15;               // A row (h) / B col (b) / C col (b)
    const int quad  = lane >> 4;               // k-quad for A/B; C row-quad (h)

    __shared__ unsigned short ldsW1[4 * HN * DN];  // 32 KB, XOR-swizzled bf16
    __shared__ unsigned short ldsX[256 * DN];      // 32 KB, XOR-swizzled bf16
    __shared__ float ldsW2[4 * HN];                // 1 KB

    const int b0 = btile * 256;

    // ---- Stage X (256 rows, coalesced fp32) -> bf16 LDS, swizzled ----
    {
        const float4* x4 = reinterpret_cast<const float4*>(X + (size_t)b0 * DN);
#pragma unroll
        for (int it = 0; it < 8; ++it) {
            int chunk = it * 256 + tid;        // 0..2047, 8 floats each (contiguous)
            int row = chunk >> 3;              // 0..255
            int c   = chunk & 7;               // 8-elem column slot
            float4 v0 = x4[chunk * 2];
            float4 v1 = x4[chunk * 2 + 1];
            int elem = row * 64 + ((c ^ (row & 7)) << 3);
            *reinterpret_cast<short8*>(&ldsX[elem]) = cvt8(v0, v1);
        }
    }

    // ---- Stage W1 * adj -> bf16 LDS, swizzled (fused w1prep) ----
    {
        const float4* w4 = reinterpret_cast<const float4*>(W1 + (size_t)ng * 4 * HN * DN);
        const float4* a4 = reinterpret_cast<const float4*>(adj + (size_t)ng * 4 * DN);
#pragma unroll
        for (int it = 0; it < 8; ++it) {
            int chunk = it * 256 + tid;        // 0..2047, 8 floats each (coalesced)
            int nl = chunk >> 9;               // node_local 0..3
            int h  = (chunk >> 3) & 63;
            int c  = chunk & 7;
            float4 w0 = w4[chunk * 2];
            float4 w1v = w4[chunk * 2 + 1];
            float4 a0 = a4[nl * 16 + c * 2];
            float4 a1 = a4[nl * 16 + c * 2 + 1];
            float4 m0 = {w0.x * a0.x, w0.y * a0.y, w0.z * a0.z, w0.w * a0.w};
            float4 m1 = {w1v.x * a1.x, w1v.y * a1.y, w1v.z * a1.z, w1v.w * a1.w};
            int elem = nl * 4096 + h * 64 + ((c ^ (h & 7)) << 3);
            *reinterpret_cast<short8*>(&ldsW1[elem]) = cvt8(m0, m1);
        }
        ldsW2[tid] = W2[ng * 256 + tid];
    }
    __syncthreads();

    // ---- X fragments from LDS (j-invariant, built once per wave) ----
    // b = b0 + wave*64 + nt*16 + row16, d = kk*32 + quad*8
    short8 xfrag[2][4];                        // [kk][nt]
#pragma unroll
    for (int kk = 0; kk < 2; ++kk)
#pragma unroll
        for (int nt = 0; nt < 4; ++nt) {
            int row_l = wave * 64 + nt * 16 + row16;
            int elem = row_l * 64 + (((kk * 4 + quad) ^ (row16 & 7)) << 3);
            xfrag[kk][nt] = *reinterpret_cast<const short8*>(&ldsX[elem]);
        }

    float res[4][4];                           // [nt][j], static indices only

#pragma unroll
    for (int j = 0; j < 4; ++j) {
        // W1' fragments (A operand): h = mt*16 + row16, d = kk*32 + quad*8
        short8 wfrag[2][4];                    // [kk][mt]
#pragma unroll
        for (int kk = 0; kk < 2; ++kk)
#pragma unroll
            for (int mt = 0; mt < 4; ++mt) {
                int h = mt * 16 + row16;
                int elem = j * 4096 + h * 64 + (((kk * 4 + quad) ^ (row16 & 7)) << 3);
                wfrag[kk][mt] = *reinterpret_cast<const short8*>(&ldsW1[elem]);
            }

        // W2[node j][h] for this lane's 4 regs per mt: h = mt*16 + quad*4 + r
        float4 w2v[4];
#pragma unroll
        for (int mt = 0; mt < 4; ++mt)
            w2v[mt] = *reinterpret_cast<const float4*>(&ldsW2[j * 64 + mt * 16 + quad * 4]);

        f32x4 acc[4][4];                       // [mt(h)][nt(b)]
#pragma unroll
        for (int mt = 0; mt < 4; ++mt)
#pragma unroll
            for (int nt = 0; nt < 4; ++nt)
                acc[mt][nt] = (f32x4){0.f, 0.f, 0.f, 0.f};

#pragma unroll
        for (int kk = 0; kk < 2; ++kk)
#pragma unroll
            for (int mt = 0; mt < 4; ++mt)
#pragma unroll
                for (int nt = 0; nt < 4; ++nt)
                    acc[mt][nt] = __builtin_amdgcn_mfma_f32_16x16x32_bf16(
                        wfrag[kk][mt], xfrag[kk][nt], acc[mt][nt], 0, 0, 0);

        // epilogue: out[b, j] = sum_h relu(C[h,b]) * W2[j,h]
        // per-lane: 16 h values (4 mt x 4 regs); cross-lane only over quad (x4)
#pragma unroll
        for (int nt = 0; nt < 4; ++nt) {
            f32x2 s = (f32x2){0.f, 0.f};
#pragma unroll
            for (int mt = 0; mt < 4; ++mt) {
                f32x2 m01 = (f32x2){fmaxf(acc[mt][nt][0], 0.f), fmaxf(acc[mt][nt][1], 0.f)};
                f32x2 m23 = (f32x2){fmaxf(acc[mt][nt][2], 0.f), fmaxf(acc[mt][nt][3], 0.f)};
                s += m01 * (f32x2){w2v[mt].x, w2v[mt].y};   // v_pk_fma_f32
                s += m23 * (f32x2){w2v[mt].z, w2v[mt].w};
            }
            float r = s[0] + s[1];
            r += __shfl_xor(r, 16);            // reduce over quad (lanes +-16, +-32)
            r += __shfl_xor(r, 32);
            res[nt][j] = r;
        }
    }

    // direct store: lane stores the row where nt == quad (all 64 rows covered)
    float4 v = make_float4(0.f, 0.f, 0.f, 0.f);
#pragma unroll
    for (int nt = 0; nt < 4; ++nt)
        if (quad == nt)
            v = make_float4(res[nt][0], res[nt][1], res[nt][2], res[nt][3]);
    int row = b0 + wave * 64 + quad * 16 + row16;
    *reinterpret_cast<float4*>(out + (size_t)row * DN + ng * 4) = v;
}

extern "C" void kernel_launch(void* const* d_in, const int* in_sizes, int n_in,
                              void* d_out, int out_size, void* d_ws, size_t ws_size,
                              hipStream_t stream) {
    const float* X   = (const float*)d_in[0];   // [B, D] fp32
    const float* adj = (const float*)d_in[1];   // [D, D] fp32
    const float* W1  = (const float*)d_in[2];   // [D, H, D] fp32
    const float* W2  = (const float*)d_in[3];   // [D, H] fp32
    float* out = (float*)d_out;                 // [B, D] fp32

    (void)d_ws; (void)ws_size;                  // workspace intentionally unused

    mlp_fused_kernel<<<64 * 16, 256, 0, stream>>>(X, adj, W1, W2, out);
}

// Round 3
// 75.407 us; speedup vs baseline: 1.0439x; 1.0063x over previous
//
#include <hip/hip_runtime.h>
#include <hip/hip_bf16.h>

// Problem constants
constexpr int BN = 16384;          // batch
constexpr int DN = 64;             // nodes / input dim
constexpr int HN = 64;             // hidden

// ws layout: [0, 2MB) Xbf images; [2MB, 2.5MB) W1bf images
constexpr int XCHUNKS  = (BN * DN) / 8;          // 131072 16B-chunks (64 tiles x 2048)
constexpr int W1CHUNKS = (DN * HN * DN) / 8;     // 32768  16B-chunks (16 ngs x 2048)
constexpr int TOTCHUNKS = XCHUNKS + W1CHUNKS;    // 163840
constexpr int PREP_BLOCKS = TOTCHUNKS / 256;     // 640

typedef __attribute__((ext_vector_type(8))) short short8;   // 8 x bf16
typedef __attribute__((ext_vector_type(4))) float f32x4;    // MFMA accumulator
typedef __attribute__((ext_vector_type(2))) float f32x2;    // packed-math pair

__device__ __forceinline__ unsigned short f2bf(float f) {
    __hip_bfloat16 h = __float2bfloat16(f);
    return *reinterpret_cast<unsigned short*>(&h);
}

__device__ __forceinline__ short8 cvt8(float4 a, float4 b) {
    short8 r;
    r[0] = (short)f2bf(a.x); r[1] = (short)f2bf(a.y);
    r[2] = (short)f2bf(a.z); r[3] = (short)f2bf(a.w);
    r[4] = (short)f2bf(b.x); r[5] = (short)f2bf(b.y);
    r[6] = (short)f2bf(b.z); r[7] = (short)f2bf(b.w);
    return r;
}

// async global->LDS, 16B per lane: dest = wave-uniform LDS base + lane*16
__device__ __forceinline__ void load_lds16(const unsigned short* g, unsigned short* l) {
    __builtin_amdgcn_global_load_lds(
        (const __attribute__((address_space(1))) unsigned int*)(const void*)g,
        (__attribute__((address_space(3))) unsigned int*)(void*)l, 16, 0, 0);
}

// ---------------------------------------------------------------------------
// Prep: write PRE-SWIZZLED bf16 LDS images into workspace so the main kernel
// can stage with global_load_lds (linear dest) and read with the XOR swizzle.
//   X image  (per 256-row btile, 32 KB): elem = row*64 + ((c^(row&7))<<3)+e
//   W1 image (per 4-node ng,   32 KB):   elem = nl*4096 + h*64 + ((c^(h&7))<<3)+e
// Writes are linear/coalesced; reads permute 16B slots within a row (same
// cache lines). All fp32->bf16 conversion + adj masking happens HERE, once.
// ---------------------------------------------------------------------------
__global__ __launch_bounds__(256) void prep_kernel(
    const float* __restrict__ X, const float* __restrict__ adj,
    const float* __restrict__ W1,
    unsigned short* __restrict__ Xbf, unsigned short* __restrict__ W1bf)
{
    int c = blockIdx.x * 256 + threadIdx.x;
    if (c < XCHUNKS) {
        int tile = c >> 11;            // 2048 chunks per 256-row tile
        int pos  = c & 2047;
        int row  = pos >> 3;           // 0..255
        int s    = pos & 7;            // swizzled slot
        int col8 = s ^ (row & 7);      // source column slot
        const float* p = X + ((size_t)tile * 256 + row) * DN + col8 * 8;
        float4 v0 = *reinterpret_cast<const float4*>(p);
        float4 v1 = *reinterpret_cast<const float4*>(p + 4);
        reinterpret_cast<short8*>(Xbf)[c] = cvt8(v0, v1);
    } else {
        int c2  = c - XCHUNKS;
        int ng  = c2 >> 11;            // 2048 chunks per 4-node group
        int pos = c2 & 2047;
        int nl  = pos >> 9;
        int h   = (pos >> 3) & 63;
        int s   = pos & 7;
        int col8 = s ^ (h & 7);
        int node = ng * 4 + nl;
        const float* wp = W1 + ((size_t)node) * HN * DN + h * DN + col8 * 8;
        const float* ap = adj + node * DN + col8 * 8;
        float4 w0 = *reinterpret_cast<const float4*>(wp);
        float4 w1v = *reinterpret_cast<const float4*>(wp + 4);
        float4 a0 = *reinterpret_cast<const float4*>(ap);
        float4 a1 = *reinterpret_cast<const float4*>(ap + 4);
        float4 m0 = {w0.x * a0.x, w0.y * a0.y, w0.z * a0.z, w0.w * a0.w};
        float4 m1 = {w1v.x * a1.x, w1v.y * a1.y, w1v.z * a1.z, w1v.w * a1.w};
        reinterpret_cast<short8*>(W1bf)[c2] = cvt8(m0, m1);
    }
}

// ---------------------------------------------------------------------------
// Main: block = (256-row btile, 4 nodes), 4 waves x 64 rows. Staging is pure
// DMA (global_load_lds dwordx4 of the pre-built images): zero staging VALU,
// zero staging VGPR round-trip, zero ds_writes. Compute loop unchanged from
// the verified round-2 kernel (transposed MFMA, packed-fma epilogue).
// ---------------------------------------------------------------------------
__global__ __launch_bounds__(256, 2) void mlp_fused_kernel(
    const unsigned short* __restrict__ Xbf,    // pre-swizzled bf16 images
    const unsigned short* __restrict__ W1bf,   // pre-swizzled bf16 images
    const float* __restrict__ W2,              // [64][64] fp32
    float* __restrict__ out)                   // [B][64] fp32
{
    const int btile = blockIdx.x & 63;         // fastest: same btile -> same XCD
    const int ng    = blockIdx.x >> 6;         // node group, 0..15
    const int tid   = threadIdx.x;
    const int wave  = tid >> 6;                // 0..3
    const int lane  = tid & 63;
    const int row16 = lane & 15;
    const int quad  = lane >> 4;

    __shared__ unsigned short ldsW1[4 * HN * DN];  // 32 KB
    __shared__ unsigned short ldsX[256 * DN];      // 32 KB
    __shared__ float ldsW2[4 * HN];                // 1 KB

    const int b0 = btile * 256;

    // ---- DMA staging: 8+8 global_load_lds_dwordx4 per thread-slot ----
    {
        const unsigned short* xsrc = Xbf + (size_t)btile * (256 * DN);
        const unsigned short* wsrc = W1bf + (size_t)ng * (4 * HN * DN);
#pragma unroll
        for (int it = 0; it < 8; ++it) {
            int chunk = it * 256 + wave * 64;      // wave-uniform chunk base
            load_lds16(xsrc + (size_t)(chunk + lane) * 8, &ldsX[chunk * 8]);
            load_lds16(wsrc + (size_t)(chunk + lane) * 8, &ldsW1[chunk * 8]);
        }
        ldsW2[tid] = W2[ng * 256 + tid];
    }
    __syncthreads();   // compiler emits s_waitcnt vmcnt(0) lgkmcnt(0) before barrier

    // ---- X fragments from LDS (j-invariant) ----
    short8 xfrag[2][4];                        // [kk][nt]
#pragma unroll
    for (int kk = 0; kk < 2; ++kk)
#pragma unroll
        for (int nt = 0; nt < 4; ++nt) {
            int row_l = wave * 64 + nt * 16 + row16;
            int elem = row_l * 64 + (((kk * 4 + quad) ^ (row16 & 7)) << 3);
            xfrag[kk][nt] = *reinterpret_cast<const short8*>(&ldsX[elem]);
        }

    float res[4][4];                           // [nt][j], static indices only

#pragma unroll
    for (int j = 0; j < 4; ++j) {
        short8 wfrag[2][4];                    // [kk][mt]
#pragma unroll
        for (int kk = 0; kk < 2; ++kk)
#pragma unroll
            for (int mt = 0; mt < 4; ++mt) {
                int h = mt * 16 + row16;
                int elem = j * 4096 + h * 64 + (((kk * 4 + quad) ^ (row16 & 7)) << 3);
                wfrag[kk][mt] = *reinterpret_cast<const short8*>(&ldsW1[elem]);
            }

        float4 w2v[4];
#pragma unroll
        for (int mt = 0; mt < 4; ++mt)
            w2v[mt] = *reinterpret_cast<const float4*>(&ldsW2[j * 64 + mt * 16 + quad * 4]);

        f32x4 acc[4][4];                       // [mt(h)][nt(b)]
#pragma unroll
        for (int mt = 0; mt < 4; ++mt)
#pragma unroll
            for (int nt = 0; nt < 4; ++nt)
                acc[mt][nt] = (f32x4){0.f, 0.f, 0.f, 0.f};

#pragma unroll
        for (int kk = 0; kk < 2; ++kk)
#pragma unroll
            for (int mt = 0; mt < 4; ++mt)
#pragma unroll
                for (int nt = 0; nt < 4; ++nt)
                    acc[mt][nt] = __builtin_amdgcn_mfma_f32_16x16x32_bf16(
                        wfrag[kk][mt], xfrag[kk][nt], acc[mt][nt], 0, 0, 0);

        // epilogue: out[b, j] = sum_h relu(C[h,b]) * W2[j,h]
#pragma unroll
        for (int nt = 0; nt < 4; ++nt) {
            f32x2 s = (f32x2){0.f, 0.f};
#pragma unroll
            for (int mt = 0; mt < 4; ++mt) {
                f32x2 m01 = (f32x2){fmaxf(acc[mt][nt][0], 0.f), fmaxf(acc[mt][nt][1], 0.f)};
                f32x2 m23 = (f32x2){fmaxf(acc[mt][nt][2], 0.f), fmaxf(acc[mt][nt][3], 0.f)};
                s += m01 * (f32x2){w2v[mt].x, w2v[mt].y};   // v_pk_fma_f32
                s += m23 * (f32x2){w2v[mt].z, w2v[mt].w};
            }
            float r = s[0] + s[1];
            r += __shfl_xor(r, 16);            // reduce over quad (lanes +-16, +-32)
            r += __shfl_xor(r, 32);
            res[nt][j] = r;
        }
    }

    // direct store: lane stores the row where nt == quad
    float4 v = make_float4(0.f, 0.f, 0.f, 0.f);
#pragma unroll
    for (int nt = 0; nt < 4; ++nt)
        if (quad == nt)
            v = make_float4(res[nt][0], res[nt][1], res[nt][2], res[nt][3]);
    int row = b0 + wave * 64 + quad * 16 + row16;
    *reinterpret_cast<float4*>(out + (size_t)row * DN + ng * 4) = v;
}

extern "C" void kernel_launch(void* const* d_in, const int* in_sizes, int n_in,
                              void* d_out, int out_size, void* d_ws, size_t ws_size,
                              hipStream_t stream) {
    const float* X   = (const float*)d_in[0];   // [B, D] fp32
    const float* adj = (const float*)d_in[1];   // [D, D] fp32
    const float* W1  = (const float*)d_in[2];   // [D, H, D] fp32
    const float* W2  = (const float*)d_in[3];   // [D, H] fp32
    float* out = (float*)d_out;                 // [B, D] fp32

    unsigned short* Xbf  = (unsigned short*)d_ws;              // 2 MB
    unsigned short* W1bf = (unsigned short*)d_ws + BN * DN;    // 512 KB

    prep_kernel<<<PREP_BLOCKS, 256, 0, stream>>>(X, adj, W1, Xbf, W1bf);
    mlp_fused_kernel<<<64 * 16, 256, 0, stream>>>(Xbf, W1bf, W2, out);
}